// Round 2
// baseline (312.847 us; speedup 1.0000x reference)
//
#include <hip/hip_runtime.h>
#include <stdint.h>

#define NROWS 8192
#define MCOLS 8192
#define KDIM  256

typedef __bf16 bf16x8 __attribute__((ext_vector_type(8)));
typedef float  floatx4 __attribute__((ext_vector_type(4)));

__device__ __forceinline__ unsigned short f32_to_bf16_rne(float f) {
    unsigned int u = __float_as_uint(f);
    u += 0x7FFFu + ((u >> 16) & 1u);   // round-to-nearest-even
    return (unsigned short)(u >> 16);
}
__device__ __forceinline__ float bf16_to_f32(unsigned short h) {
    return __uint_as_float(((unsigned int)h) << 16);
}

// async 16B global -> LDS (wave-uniform base + lane*16 pattern required)
__device__ __forceinline__ void async16(const void* g, void* l) {
    __builtin_amdgcn_global_load_lds(
        (const __attribute__((address_space(1))) unsigned int*)g,
        (__attribute__((address_space(3))) unsigned int*)l,
        16, 0, 0);
}

// ---------------- kernel 1: alpha = softmax(alpha_raw^2), sa = sqrt(alpha) ----
__global__ void prep_alpha(const float* __restrict__ araw, float* __restrict__ sa) {
    __shared__ float buf[256];
    int d = threadIdx.x;
    float z = araw[d];
    z = z * z;
    buf[d] = z;
    __syncthreads();
    for (int s = 128; s > 0; s >>= 1) {
        if (d < s) buf[d] = fmaxf(buf[d], buf[d + s]);
        __syncthreads();
    }
    float mx = buf[0];
    __syncthreads();
    float e = __expf(z - mx);
    buf[d] = e;
    __syncthreads();
    for (int s = 128; s > 0; s >>= 1) {
        if (d < s) buf[d] += buf[d + s];
        __syncthreads();
    }
    float sum = buf[0];
    sa[d] = sqrtf(e / sum);
}

// ---------------- kernel 2: fused row prep for BOTH matrices ----------------
// wave-per-row, no __syncthreads. Each lane handles 4 dims (float4 / ushort4).
__global__ __launch_bounds__(256) void prep_rows_all(
    const float* __restrict__ x1, const float* __restrict__ x2,
    const float* __restrict__ sa,
    unsigned short* __restrict__ Amat, unsigned short* __restrict__ Bmat,
    float* __restrict__ ra, float* __restrict__ rb)
{
    int rg   = blockIdx.x * 4 + (threadIdx.x >> 6);   // global row 0..16383
    int lane = threadIdx.x & 63;

    const float* x; unsigned short* mat; float* rn; int row;
    if (rg < NROWS) { x = x1; mat = Amat; rn = ra; row = rg; }
    else            { x = x2; mat = Bmat; rn = rb; row = rg - NROWS; }

    float4 sv = ((const float4*)sa)[lane];
    float4 xv = ((const float4*)(x + (size_t)row * KDIM))[lane];

    unsigned short h0 = f32_to_bf16_rne(xv.x * sv.x);
    unsigned short h1 = f32_to_bf16_rne(xv.y * sv.y);
    unsigned short h2 = f32_to_bf16_rne(xv.z * sv.z);
    unsigned short h3 = f32_to_bf16_rne(xv.w * sv.w);

    ushort4 hv; hv.x = h0; hv.y = h1; hv.z = h2; hv.w = h3;
    ((ushort4*)(mat + (size_t)row * KDIM))[lane] = hv;

    float f0 = bf16_to_f32(h0), f1 = bf16_to_f32(h1),
          f2 = bf16_to_f32(h2), f3 = bf16_to_f32(h3);
    float nrm = f0 * f0 + f1 * f1 + f2 * f2 + f3 * f3;
#pragma unroll
    for (int off = 32; off > 0; off >>= 1)
        nrm += __shfl_down(nrm, off, 64);
    if (lane == 0) rn[row] = nrm;
}

// ---------------- kernel 3: NT-GEMM + fused RBF epilogue ---------------------
// C[i,j] = sum_k A[i,k]*B[j,k];  out = var*exp(min(C - 0.5*(ra_i+rb_j), 0))
// Tile 128x128, BK=64, 4 waves (2x2), each wave 64x64 via 4x4 of 16x16x32 MFMA.
// MFMA operands SWAPPED (bf, af): lane&15 -> output row i, quad*4+reg -> 4
// consecutive output cols j => float4 nontemporal stores.
__global__ __launch_bounds__(256) void rbf_gemm(
    const unsigned short* __restrict__ A, const unsigned short* __restrict__ B,
    const float* __restrict__ ra, const float* __restrict__ rb,
    const float* __restrict__ vraw, float* __restrict__ out)
{
    __shared__ unsigned short As[128 * 64];
    __shared__ unsigned short Bs[128 * 64];

    const int tid  = threadIdx.x;
    const int lane = tid & 63;
    const int wave = tid >> 6;

    // 8-wide supertile swizzle: 8 A-row-tiles reuse the full B panel in L2/L3
    const int lin = blockIdx.y * gridDim.x + blockIdx.x;
    const int p   = lin >> 9;           // / (8*64)
    const int w   = lin & 511;
    const int bm  = (p << 3) + (w & 7);
    const int bn  = w >> 3;

    const int wm = (wave & 1) * 64;
    const int wn = (wave >> 1) * 64;
    const int quad = lane >> 4;
    const int l15  = lane & 15;

    floatx4 acc[4][4];
#pragma unroll
    for (int i = 0; i < 4; i++)
#pragma unroll
        for (int j = 0; j < 4; j++) acc[i][j] = (floatx4)0.0f;

    for (int k0 = 0; k0 < KDIM; k0 += 64) {
#pragma unroll
        for (int it = 0; it < 4; ++it) {
            int c   = it * 256 + tid;      // 16B chunk index 0..1023
            int row = c >> 3;              // tile row 0..127
            int kc  = c & 7;               // chunk-of-8-bf16 within BK=64
            int gkc = kc ^ (row & 7);      // XOR swizzle on the global side
            const unsigned short* gA = A + (size_t)(bm * 128 + row) * KDIM + k0 + gkc * 8;
            const unsigned short* gB = B + (size_t)(bn * 128 + row) * KDIM + k0 + gkc * 8;
            async16(gA, &As[c * 8]);
            async16(gB, &Bs[c * 8]);
        }
        __syncthreads();

#pragma unroll
        for (int ks = 0; ks < 2; ++ks) {
            bf16x8 af[4], bfr[4];
            int kc = ks * 4 + quad;        // k = ks*32 + quad*8 -> chunk index
#pragma unroll
            for (int t = 0; t < 4; ++t) {
                int m  = wm + t * 16 + l15;
                int sa_ = m * 8 + (kc ^ (m & 7));
                af[t]  = *(const bf16x8*)&As[sa_ * 8];
                int n  = wn + t * 16 + l15;
                int sb_ = n * 8 + (kc ^ (n & 7));
                bfr[t] = *(const bf16x8*)&Bs[sb_ * 8];
            }
            // SWAPPED operands: row(quad*4+reg) <- B index j, col(l15) <- A index i
#pragma unroll
            for (int ti = 0; ti < 4; ++ti)
#pragma unroll
                for (int tj = 0; tj < 4; ++tj)
                    acc[ti][tj] = __builtin_amdgcn_mfma_f32_16x16x32_bf16(
                        bfr[tj], af[ti], acc[ti][tj], 0, 0, 0);
        }
        __syncthreads();
    }

    // epilogue: for fragment (ti,tj): i = wm+ti*16+l15 (fixed per lane),
    // j = wn+tj*16+quad*4+reg (4 consecutive) -> float4 nontemporal store
    float variance = vraw[0] * vraw[0];
    float hra[4];
#pragma unroll
    for (int ti = 0; ti < 4; ++ti)
        hra[ti] = -0.5f * ra[bm * 128 + wm + ti * 16 + l15];

#pragma unroll
    for (int tj = 0; tj < 4; ++tj) {
        int jbase = bn * 128 + wn + tj * 16 + quad * 4;
        float4 rb4 = *(const float4*)(rb + jbase);
        float hrb0 = -0.5f * rb4.x, hrb1 = -0.5f * rb4.y,
              hrb2 = -0.5f * rb4.z, hrb3 = -0.5f * rb4.w;
#pragma unroll
        for (int ti = 0; ti < 4; ++ti) {
            int i = bm * 128 + wm + ti * 16 + l15;
            floatx4 v;
            v[0] = variance * __expf(fminf(acc[ti][tj][0] + hra[ti] + hrb0, 0.0f));
            v[1] = variance * __expf(fminf(acc[ti][tj][1] + hra[ti] + hrb1, 0.0f));
            v[2] = variance * __expf(fminf(acc[ti][tj][2] + hra[ti] + hrb2, 0.0f));
            v[3] = variance * __expf(fminf(acc[ti][tj][3] + hra[ti] + hrb3, 0.0f));
            __builtin_nontemporal_store(v, (floatx4*)(out + (size_t)i * MCOLS + jbase));
        }
    }
}

extern "C" void kernel_launch(void* const* d_in, const int* in_sizes, int n_in,
                              void* d_out, int out_size, void* d_ws, size_t ws_size,
                              hipStream_t stream) {
    const float* x1   = (const float*)d_in[0];
    const float* x2   = (const float*)d_in[1];
    const float* araw = (const float*)d_in[2];
    const float* vraw = (const float*)d_in[3];
    float* out = (float*)d_out;

    char* ws = (char*)d_ws;
    float* sa = (float*)ws;                               // 256 f32   @ 0
    float* ra = (float*)(ws + 1024);                      // 8192 f32  @ 1 KiB
    float* rb = (float*)(ws + 1024 + 32768);              // 8192 f32
    unsigned short* Amat = (unsigned short*)(ws + 66560);                            // 4 MiB bf16
    unsigned short* Bmat = (unsigned short*)(ws + 66560 + (size_t)NROWS * KDIM * 2); // 4 MiB bf16

    prep_alpha<<<1, 256, 0, stream>>>(araw, sa);
    prep_rows_all<<<(NROWS + MCOLS) / 4, 256, 0, stream>>>(x1, x2, sa, Amat, Bmat, ra, rb);

    dim3 grid(MCOLS / 128, NROWS / 128);
    rbf_gemm<<<grid, 256, 0, stream>>>(Amat, Bmat, ra, rb, vraw, out);
}